// Round 11
// baseline (10201.065 us; speedup 1.0000x reference)
//
#include <hip/hip_runtime.h>

#define Hdim 64
#define Tlen 16384
#define Bsz  16
#define LOG2E 1.44269504088896340736f

typedef _Float16 half8 __attribute__((ext_vector_type(8)));
typedef float    f32x4 __attribute__((ext_vector_type(4)));

__device__ __forceinline__ float sigm(float x) {
    return __builtin_amdgcn_rcpf(1.0f + __builtin_amdgcn_exp2f(-LOG2E * x));
}
__device__ __forceinline__ float tanhfast(float x) {
    const float e = __builtin_amdgcn_exp2f((2.0f * LOG2E) * x);
    return fmaf(-2.0f, __builtin_amdgcn_rcpf(e + 1.0f), 1.0f);
}

// Raw LDS-only barrier: waits DS ops (lgkmcnt) but lets global stores stay
// in flight. __syncthreads() would emit s_waitcnt vmcnt(0) before s_barrier,
// draining the per-step y/c stores to L2-ack => the ~1300 cyc/step floor of
// rounds 1-9. "memory" clobber + sched_barrier(0) stop the backend from
// hoisting post-barrier ds_reads above the barrier (rule #18).
#define BAR_LDS() do {                                                   \
    asm volatile("s_waitcnt lgkmcnt(0)\n\ts_barrier" ::: "memory");      \
    __builtin_amdgcn_sched_barrier(0);                                   \
} while (0)

__global__ void __launch_bounds__(256)
__attribute__((amdgpu_waves_per_eu(1, 1)))
apdl_rnn_mfma(const float* __restrict__ x,
              const float* __restrict__ W_ih,
              const float* __restrict__ W_hh,
              const float* __restrict__ b_ih,
              const float* __restrict__ b_hh,
              float* __restrict__ out)
{
    // LDS: W frags 32KB + ap dbuf 4KB + x dbuf (padded) ~8.7KB + bias/wih 2KB
    __shared__ _Float16 wfrag[16 * 2 * 64 * 8];
    __shared__ char     apraw[2][2048];
    __shared__ float    xbuf[2][64][17];       // pad 16->17: staging writes 2-way, not 16-way
    __shared__ float    bias_lds[256];
    __shared__ float    wih_lds[256];

    const int tid = threadIdx.x;
    const int w   = tid >> 6;       // wave id: owns j-slice [w*16, w*16+16) of ALL 4 gates
    const int l   = tid & 63;
    const int b   = l & 15;         // batch (MFMA N / C-col)
    const int g16 = l >> 4;
    const int j0  = w * 16 + g16 * 4;  // this lane's 4 hidden indices j0..j0+3

    bias_lds[tid] = b_ih[tid] + b_hh[tid];
    wih_lds[tid]  = W_ih[tid];      // I == 1

    // ---- pack W_hh into MFMA A-fragment order (f16) ----
    // tile T (16 rows of G^T), chunk c (K 32-slice); lane vl holds
    // A[row=vl&15][k=(vl>>4)*8 + 0..8] stored lane-contiguous (conflict-free b128).
    {
        const int T = tid >> 4, s = tid & 15;
        #pragma unroll
        for (int q = 0; q < 4; ++q) {
            const int vl  = s * 4 + q;
            const int row = T * 16 + (vl & 15);
            #pragma unroll
            for (int c = 0; c < 2; ++c) {
                const int kb = c * 32 + (vl >> 4) * 8;
                half8 tmp;
                #pragma unroll
                for (int i = 0; i < 8; ++i)
                    tmp[i] = (_Float16)W_hh[row * 64 + kb + i];
                *(half8*)&wfrag[((T * 2 + c) * 64 + vl) * 8] = tmp;
            }
        }
    }
    __syncthreads();               // one-time; full drain harmless here

    // Hoist loop-invariant operands to regs
    half8 af[4][2];                 // W frags: gate g, K-chunk c (tile = g*4+w)
    f32x4 bias4[4], wih4[4];
    #pragma unroll
    for (int g = 0; g < 4; ++g) {
        #pragma unroll
        for (int c = 0; c < 2; ++c)
            af[g][c] = *(const half8*)&wfrag[(g * 8 + w * 2 + c) * 512 + l * 8];
        bias4[g] = *(const f32x4*)&bias_lds[g * 64 + j0];
        wih4[g]  = *(const f32x4*)&wih_lds[g * 64 + j0];
    }

    // ap tile addressing: row b (128B), XOR-swizzle bits 4..6 with b&7
    const int swz     = (b & 7) << 4;
    const int wr_off  = b * 128 + ((w * 32 + g16 * 8) ^ swz);   // 8B write: (b, j0..j0+3)
    const int rd0_off = b * 128 + ((g16 * 16) ^ swz);           // 16B read: (b, g16*8 + 0..8)
    const int rd1_off = b * 128 + ((64 + g16 * 16) ^ swz);      // 16B read: +32 j

    const float apcK = 0.8375f;     // (1-alpha)/(1+alpha) exactly
    f32x4 aph = {0,0,0,0}, apcv = {0,0,0,0};
    f32x4 h1v = {0,0,0,0}, c1v = {0,0,0,0};
    f32x4 h2v = {0,0,0,0}, c2v = {0,0,0,0};
    const f32x4 zero4 = {0,0,0,0};

    float* yp = out + (size_t)b * Tlen * Hdim + j0;
    float* cp = yp + (size_t)Bsz * Tlen * Hdim;

    const int st_b = tid >> 4;          // x staging: batch
    const int st_t = (tid & 15) * 4;    // x staging: t offset

    // x prefetch register: holds block t..t+64 ahead of its staging step
    float4 xreg = *(const float4*)&x[(size_t)st_b * Tlen + st_t];

    auto step = [&](int t, int par, f32x4& h_prev, f32x4& c_prev,
                    f32x4& h_prev2, f32x4& c_prev2) {
        // stage x block (loaded 64 steps ago into xreg); issue next block's load
        if ((t & 63) == 0) {
            const int buf = (t >> 6) & 1;
            xbuf[buf][st_t + 0][st_b] = xreg.x;
            xbuf[buf][st_t + 1][st_b] = xreg.y;
            xbuf[buf][st_t + 2][st_b] = xreg.z;
            xbuf[buf][st_t + 3][st_b] = xreg.w;
            if (t + 64 < Tlen)
                xreg = *(const float4*)&x[(size_t)st_b * Tlen + (t + 64) + st_t];
        }
        // allpass: ap_t = apc*(hc_{t-1} - ap_{t-1}) + hc_{t-2}   (lane-local)
        #pragma unroll
        for (int r = 0; r < 4; ++r) {
            aph[r]  = fmaf(apcK, h_prev[r] - aph[r],  h_prev2[r]);
            apcv[r] = fmaf(apcK, c_prev[r] - apcv[r], c_prev2[r]);
        }
        // publish ap_h (f16) for everyone's B-fragment
        union { _Float16 h[4]; uint2 u; } pk;
        #pragma unroll
        for (int r = 0; r < 4; ++r) pk.h[r] = (_Float16)aph[r];
        *(uint2*)(apraw[par] + wr_off) = pk.u;

        BAR_LDS();                     // LDS fence + barrier; stores stay in flight

        const float xv  = xbuf[(t >> 6) & 1][t & 63][b];
        const half8 bf0 = *(const half8*)(apraw[par] + rd0_off);
        const half8 bf1 = *(const half8*)(apraw[par] + rd1_off);

        // G^T tiles: acc[g][r] = gate g, row j0+r, batch b.
        // Two INDEPENDENT MFMAs per gate (no C-chain), summed on VALU.
        f32x4 acc[4];
        #pragma unroll
        for (int g = 0; g < 4; ++g) {
            f32x4 ci;
            #pragma unroll
            for (int r = 0; r < 4; ++r) ci[r] = fmaf(xv, wih4[g][r], bias4[g][r]);
            const f32x4 p0 = __builtin_amdgcn_mfma_f32_16x16x32_f16(af[g][0], bf0, ci,    0, 0, 0);
            const f32x4 p1 = __builtin_amdgcn_mfma_f32_16x16x32_f16(af[g][1], bf1, zero4, 0, 0, 0);
            acc[g] = p0 + p1;
        }

        // epilogue fully in-register: this lane owns i,f,g,o of its 4 elems
        f32x4 hn, cn;
        #pragma unroll
        for (int r = 0; r < 4; ++r) {
            const float ig = sigm(acc[0][r]);
            const float fg = sigm(acc[1][r]);
            const float gg = tanhfast(acc[2][r]);
            const float og = sigm(acc[3][r]);
            cn[r] = fmaf(fg, apcv[r], ig * gg);
            hn[r] = og * tanhfast(cn[r]);
        }
        *(f32x4*)yp = hn;              // fire-and-forget; never drained in-loop
        *(f32x4*)cp = cn;
        yp += Hdim; cp += Hdim;
        h_prev2 = hn; c_prev2 = cn;    // caller's swap renames states
    };

    for (int t = 0; t < Tlen; t += 2) {
        step(t,     0, h1v, c1v, h2v, c2v);   // writes h_t   into h2v
        step(t + 1, 1, h2v, c2v, h1v, c1v);   // writes h_t+1 into h1v
    }

    // ap_final = ap used by the last cell (B, 2H)
    float* apf = out + 2 * (size_t)Bsz * Tlen * Hdim + (size_t)b * 2 * Hdim + j0;
    *(f32x4*)apf          = aph;
    *(f32x4*)(apf + Hdim) = apcv;
}

extern "C" void kernel_launch(void* const* d_in, const int* in_sizes, int n_in,
                              void* d_out, int out_size, void* d_ws, size_t ws_size,
                              hipStream_t stream) {
    const float* x    = (const float*)d_in[0];
    const float* W_ih = (const float*)d_in[1];
    const float* W_hh = (const float*)d_in[2];
    const float* b_ih = (const float*)d_in[3];
    const float* b_hh = (const float*)d_in[4];
    float* out = (float*)d_out;

    apdl_rnn_mfma<<<dim3(1), dim3(256), 0, stream>>>(x, W_ih, W_hh, b_ih, b_hh, out);
}